// Round 9
// baseline (2543.849 us; speedup 1.0000x reference)
//
#include <hip/hip_runtime.h>
#include <math.h>

namespace {

typedef unsigned short u16;
typedef __attribute__((ext_vector_type(4))) float f32x4;
typedef __attribute__((ext_vector_type(8))) _Float16 f16x8;
typedef __attribute__((ext_vector_type(4))) _Float16 f16x4;
typedef __attribute__((ext_vector_type(2))) _Float16 f16x2;

constexpr int B = 32;
constexpr int M = 600;
constexpr int H = 256;
constexpr int TSTEPS = 4;
constexpr int HP = 4096;          // H*P
constexpr int BM = B * M;         // 19200
constexpr int TWOH = 512;
constexpr int THREEH = 768;
constexpr int FOURH = 1024;
constexpr int FIVEH = 1280;
constexpr int NTILES = BM / 128;  // 150 row tiles (128-row granularity — r5 winner)

__device__ __forceinline__ float sigf(float x) { return 1.0f / (1.0f + expf(-x)); }

__device__ __forceinline__ void gload16(const u16* g, u16* l) {
    __builtin_amdgcn_global_load_lds(
        (const __attribute__((address_space(1))) void*)g,
        (__attribute__((address_space(3))) void*)l, 16, 0, 0);
}

// ---------------- init ----------------
__global__ void k_init(const int* __restrict__ d_mask,
                       float* __restrict__ h, float* __restrict__ c,
                       float* __restrict__ loss_vec,
                       int* __restrict__ s_i, int* __restrict__ e_i,
                       int* __restrict__ p1r, int* __restrict__ p2r)
{
    int tid = threadIdx.x;
    for (int i = tid; i < B * H; i += 256) { h[i] = 0.f; c[i] = 0.f; }
    if (tid < B) {
        loss_vec[tid] = 0.f;
        s_i[tid] = 0;
        int s = 0;
        const int* row = d_mask + tid * M;
        for (int m = 0; m < M; ++m) s += row[m];
        e_i[tid] = s - 1;
        p1r[tid] = 0; p2r[tid] = 0;
    }
}

// ---------------- per-128-row-tile skip flags (1 = fully masked) ----------------
__global__ __launch_bounds__(128) void k_flags(const int* __restrict__ d_mask,
                                               int* __restrict__ flags)
{
    int bm = blockIdx.x * 128 + threadIdx.x;
    int cnt = __syncthreads_count(d_mask[bm]);
    if (threadIdx.x == 0) flags[blockIdx.x] = (cnt == 0) ? 1 : 0;
}

// ---------------- gather u_cat = [U[b, s_i], U[b, e_i]] (tier-3 path only) -------
__global__ __launch_bounds__(256) void k_gather(
    const float* __restrict__ U, const int* __restrict__ s_i,
    const int* __restrict__ e_i, float* __restrict__ u_cat)
{
    int idx = blockIdx.x * 256 + threadIdx.x;   // B*512 threads
    int b = idx >> 9, k = idx & 511;
    u_cat[b * FOURH + k]       = U[((size_t)b * M + s_i[b]) * TWOH + k];
    u_cat[b * FOURH + 512 + k] = U[((size_t)b * M + e_i[b]) * TWOH + k];
}

// ---------------- LSTM gemm, u_cat read directly from U via indices ----------------
__global__ __launch_bounds__(256) void k_lstm_gemm2(
    const float* __restrict__ U, const int* __restrict__ s_i,
    const int* __restrict__ e_i, const float* __restrict__ h,
    const float* __restrict__ W_ih, const float* __restrict__ W_hh,
    const float* __restrict__ b_ih, const float* __restrict__ b_hh,
    float* __restrict__ g)
{
    int idx = blockIdx.x * 256 + threadIdx.x;   // B*1024 threads
    int b = idx >> 10, j = idx & 1023;
    const float* us = U + ((size_t)b * M + s_i[b]) * TWOH;
    const float* ue = U + ((size_t)b * M + e_i[b]) * TWOH;
    float acc = 0.f;
    const float4* x4 = (const float4*)us;
    const float4* wi4 = (const float4*)(W_ih + (size_t)j * FOURH);
    #pragma unroll 4
    for (int k = 0; k < TWOH / 4; ++k) {
        float4 a = x4[k], w = wi4[k];
        acc += a.x * w.x + a.y * w.y + a.z * w.z + a.w * w.w;
    }
    const float4* y4 = (const float4*)ue;
    const float4* wi4b = wi4 + TWOH / 4;
    #pragma unroll 4
    for (int k = 0; k < TWOH / 4; ++k) {
        float4 a = y4[k], w = wi4b[k];
        acc += a.x * w.x + a.y * w.y + a.z * w.z + a.w * w.w;
    }
    const float4* h4 = (const float4*)(h + b * H);
    const float4* wh4 = (const float4*)(W_hh + (size_t)j * H);
    #pragma unroll 4
    for (int k = 0; k < H / 4; ++k) {
        float4 a = h4[k], w = wh4[k];
        acc += a.x * w.x + a.y * w.y + a.z * w.z + a.w * w.w;
    }
    g[idx] = acc + b_ih[j] + b_hh[j];
}

// (tier-3 fallback keeps old u_cat-based version)
__global__ __launch_bounds__(256) void k_lstm_gemm(
    const float* __restrict__ u_cat, const float* __restrict__ h,
    const float* __restrict__ W_ih, const float* __restrict__ W_hh,
    const float* __restrict__ b_ih, const float* __restrict__ b_hh,
    float* __restrict__ g)
{
    int idx = blockIdx.x * 256 + threadIdx.x;   // B*1024 threads
    int b = idx >> 10, j = idx & 1023;
    float acc = 0.f;
    const float4* x4 = (const float4*)(u_cat + b * FOURH);
    const float4* wi4 = (const float4*)(W_ih + (size_t)j * FOURH);
    #pragma unroll 4
    for (int k = 0; k < FOURH / 4; ++k) {
        float4 a = x4[k], w = wi4[k];
        acc += a.x * w.x + a.y * w.y + a.z * w.z + a.w * w.w;
    }
    const float4* h4 = (const float4*)(h + b * H);
    const float4* wh4 = (const float4*)(W_hh + (size_t)j * H);
    #pragma unroll 4
    for (int k = 0; k < H / 4; ++k) {
        float4 a = h4[k], w = wh4[k];
        acc += a.x * w.x + a.y * w.y + a.z * w.z + a.w * w.w;
    }
    g[idx] = acc + b_ih[j] + b_hh[j];
}

__global__ __launch_bounds__(256) void k_lstm_gates(
    const float* __restrict__ g, float* __restrict__ h, float* __restrict__ c)
{
    int idx = blockIdx.x * 256 + threadIdx.x;   // B*H
    int b = idx >> 8, i = idx & (H - 1);
    const float* gr = g + b * FOURH;
    float gi = gr[i], gf = gr[H + i], gg = gr[2 * H + i], go = gr[3 * H + i];
    float cn = sigf(gf) * c[idx] + sigf(gi) * tanhf(gg);
    c[idx] = cn;
    h[idx] = sigf(go) * tanhf(cn);
}

// ------- r = tanh([h | U[b,s_i] | U[b,e_i]] @ W_lin.T), 4-way K-split -------
__global__ __launch_bounds__(256) void k_r2(
    const float* __restrict__ h, const float* __restrict__ U,
    const int* __restrict__ s_i, const int* __restrict__ e_i,
    const float* __restrict__ W_lin, float* __restrict__ r)
{
    int gid = blockIdx.x * 256 + threadIdx.x;   // B*H*4 threads (128 blocks)
    int out = gid >> 2;
    int part = gid & 3;
    int b = out >> 8, i = out & (H - 1);
    const float4* w4 = (const float4*)(W_lin + (size_t)i * FIVEH);
    const float4* h4 = (const float4*)(h + b * H);
    const float4* us4 = (const float4*)(U + ((size_t)b * M + s_i[b]) * TWOH);
    const float4* ue4 = (const float4*)(U + ((size_t)b * M + e_i[b]) * TWOH);
    // concat layout in float4 units: h [0,64), u_s [64,192), u_e [192,320)
    float acc = 0.f;
    int k0 = part * 80;
    #pragma unroll 4
    for (int kk = k0; kk < k0 + 80; ++kk) {
        float4 a;
        if (kk < 64) a = h4[kk];
        else if (kk < 192) a = us4[kk - 64];
        else a = ue4[kk - 192];
        float4 ww = w4[kk];
        acc += a.x * ww.x + a.y * ww.y + a.z * ww.z + a.w * ww.w;
    }
    acc += __shfl_xor(acc, 1);
    acc += __shfl_xor(acc, 2);
    if (part == 0) r[out] = tanhf(acc);
}

// (tier-3 fallback keeps old u_cat-based version)
__global__ __launch_bounds__(256) void k_r(
    const float* __restrict__ h, const float* __restrict__ u_cat,
    const float* __restrict__ W_lin, float* __restrict__ r)
{
    int idx = blockIdx.x * 256 + threadIdx.x;   // B*H
    int b = idx >> 8, i = idx & (H - 1);
    const float* w = W_lin + (size_t)i * FIVEH;
    float acc = 0.f;
    const float4* h4 = (const float4*)(h + b * H);
    const float4* w4 = (const float4*)w;
    #pragma unroll 4
    for (int k = 0; k < H / 4; ++k) {
        float4 a = h4[k], ww = w4[k];
        acc += a.x * ww.x + a.y * ww.y + a.z * ww.z + a.w * ww.w;
    }
    const float4* x4 = (const float4*)(u_cat + b * FOURH);
    const float4* w4b = (const float4*)(w + H);
    #pragma unroll 4
    for (int k = 0; k < FOURH / 4; ++k) {
        float4 a = x4[k], ww = w4b[k];
        acc += a.x * ww.x + a.y * ww.y + a.z * ww.z + a.w * ww.w;
    }
    r[idx] = tanhf(acc);
}

// ---------------- old strided rW (tier 3) ----------------
__global__ __launch_bounds__(256) void k_rW(
    const float* __restrict__ r, const float* __restrict__ W1,
    const float* __restrict__ b1, float* __restrict__ rW)
{
    int idx = blockIdx.x * 256 + threadIdx.x;   // B*HP
    int b = idx >> 12, j = idx & (HP - 1);
    const float4* r4 = (const float4*)(r + b * H);
    const float4* w4 = (const float4*)(W1 + (size_t)j * THREEH + TWOH);
    float acc = 0.f;
    #pragma unroll 4
    for (int k = 0; k < H / 4; ++k) {
        float4 a = r4[k], w = w4[k];
        acc += a.x * w.x + a.y * w.y + a.z * w.z + a.w * w.w;
    }
    rW[idx] = acc + b1[j];
}

// ------- coalesced rW via fp16 transposed weight, 2 cols/thread -------
__global__ __launch_bounds__(256) void k_rW2h(
    const float* __restrict__ r, const _Float16* __restrict__ Wt,
    const float* __restrict__ b1, float* __restrict__ rW)
{
    const int b = blockIdx.y;
    const int j = (blockIdx.x * 256 + threadIdx.x) * 2;
    __shared__ float sr[256];
    sr[threadIdx.x] = r[b * H + threadIdx.x];
    __syncthreads();
    float a0 = b1[j], a1 = b1[j + 1];
    #pragma unroll 4
    for (int k = 0; k < H; ++k) {
        f16x2 wv = *(const f16x2*)(Wt + (size_t)k * HP + j);
        float x = sr[k];
        a0 += x * (float)wv[0];
        a1 += x * (float)wv[1];
    }
    rW[(size_t)b * HP + j]     = a0;
    rW[(size_t)b * HP + j + 1] = a1;
}

// ------- LDS-tiled transpose W1[:, 512:768] -> fp16 Wt[256][4096] -------
__global__ __launch_bounds__(256) void k_transp2(
    const float* __restrict__ W, _Float16* __restrict__ Wt)
{
    __shared__ float s[32][33];
    int j0 = (blockIdx.x & 127) << 5;           // 128 j-tiles
    int k0 = (blockIdx.x >> 7) << 5;            // 8 k-tiles
    int tx = threadIdx.x & 31, ty = threadIdx.x >> 5;
    #pragma unroll
    for (int kk = 0; kk < 4; ++kk) {
        int jl = ty + kk * 8;
        s[jl][tx] = W[(size_t)(j0 + jl) * THREEH + TWOH + k0 + tx];
    }
    __syncthreads();
    #pragma unroll
    for (int kk = 0; kk < 4; ++kk) {
        int kl = ty + kk * 8;
        Wt[(size_t)(k0 + kl) * HP + j0 + tx] = (_Float16)s[tx][kl];
    }
}

// ---------------- fp32 -> fp16 converter ----------------
__global__ __launch_bounds__(256) void k_cvtH(
    const float* __restrict__ src, int ld, int Kc, _Float16* __restrict__ dst)
{
    int i4 = blockIdx.x * 256 + threadIdx.x;    // over N*Kc/4
    int perrow = Kc >> 2;
    int row = i4 / perrow;
    int kc = (i4 - row * perrow) << 2;
    float4 v = *(const float4*)(src + (size_t)row * ld + kc);
    f16x4 o;
    o[0] = (_Float16)v.x; o[1] = (_Float16)v.y; o[2] = (_Float16)v.z; o[3] = (_Float16)v.w;
    *(f16x4*)(dst + (size_t)row * Kc + kc) = o;
}

// ---- fp16 MFMA GEMM: 128x128 tile, BK=32, 256 threads (2x2 waves of 64x64) ----
// r5 winner + r8 XCD swizzle + NEW r9: T4 counted-vmcnt 3-buffer pipeline.
// Old loop issued stage(it+1) BEFORE __syncthreads, whose vmcnt(0) fully drained
// it -> entire L2/HBM latency exposed at every barrier (the measured 79% stall,
// MfmaUtil 21%). New loop: {s_waitcnt vmcnt(4); s_barrier} in ONE asm block
// (memory clobber pins ordering), leaving stage(it+1)'s 4 loads in flight
// across the barrier; stage(it+2) issued AFTER the barrier into the buffer
// consumed at it-1 (all waves past it => race-free). Last iter: vmcnt(0).
// LDS 3x16KB = 48KB -> still 3 blocks/CU (occupancy preserved, the r6 lesson).
// skip[tile]=1 -> fully-masked row tile, early exit.
// EPI=1: +bias[col], max over 16-col groups -> Ch fp16 [rows x 256]      (m2)
// EPI=3: +rW[row/M][col], max over 16-col groups -> Ch fp16 [rows x 256] (m1)
// EPI=4: plain store fp16 C [rows x 4096] into Ch                        (precompute)
template <int EPI>
__global__ __launch_bounds__(256, 4) void gemmJ(
    const _Float16* __restrict__ A, const _Float16* __restrict__ Bw,
    int K, const float* __restrict__ extra, const int* __restrict__ skip,
    float* __restrict__ Cf, _Float16* __restrict__ Ch)
{
    // ---- XCD swizzle (kept from r8: time-neutral, fixes 3.4x write amplif.) ----
    const int nwgx = gridDim.x;                  // 32
    const int nwg  = nwgx * gridDim.y;           // 4800 (mult of 8)
    int bid = blockIdx.y * nwgx + blockIdx.x;
    const int cpx = nwg >> 3;
    bid = (bid & 7) * cpx + (bid >> 3);
    const int bx = bid % nwgx, by = bid / nwgx;

    if (skip[by]) return;
    __shared__ __align__(16) u16 sA[3][128 * 32];
    __shared__ __align__(16) u16 sB[3][128 * 32];
    const int tid = threadIdx.x;
    const int w = tid >> 6, lane = tid & 63;
    const int row0 = by * 128, col0 = bx * 128;
    const int wm = w & 1, wn = w >> 1;          // 2x2 wave grid, 64x64 each

    const int r1g = tid >> 2,        k1 = (tid & 3) ^ ((r1g >> 1) & 3);
    const int r2g = (tid + 256) >> 2, k2 = ((tid + 256) & 3) ^ ((r2g >> 1) & 3);
    const size_t gA1 = (size_t)(row0 + r1g) * K + k1 * 8;
    const size_t gA2 = (size_t)(row0 + r2g) * K + k2 * 8;
    const size_t gB1 = (size_t)(col0 + r1g) * K + k1 * 8;
    const size_t gB2 = (size_t)(col0 + r2g) * K + k2 * 8;

    f32x4 acc[4][4] = {};
    const int iters = K >> 5;

    auto stage = [&](int itx, int bufi) {
        const int k0n = itx << 5;
        gload16((const u16*)(A  + gA1 + k0n), &sA[bufi][tid * 8]);
        gload16((const u16*)(A  + gA2 + k0n), &sA[bufi][(tid + 256) * 8]);
        gload16((const u16*)(Bw + gB1 + k0n), &sB[bufi][tid * 8]);
        gload16((const u16*)(Bw + gB2 + k0n), &sB[bufi][(tid + 256) * 8]);
    };
    stage(0, 0);
    if (iters > 1) stage(1, 1);

    const int mrow = lane & 15;
    const int kg = lane >> 4;
    const int slot = kg ^ ((mrow >> 1) & 3);
    const int eoff = slot << 3;

    int cur = 0, pre = 2;
    for (int it = 0; it < iters; ++it) {
        // Counted vmcnt: stage(it) complete (4 oldest of <=8 outstanding),
        // stage(it+1) stays in flight across the barrier. Single asm block
        // so nothing is scheduled between the wait and the barrier.
        if (it + 1 < iters)
            asm volatile("s_waitcnt vmcnt(4)\n\ts_barrier" ::: "memory");
        else
            asm volatile("s_waitcnt vmcnt(0)\n\ts_barrier" ::: "memory");
        if (it + 2 < iters) stage(it + 2, pre);
        const u16* pa = &sA[cur][(wm * 64 + mrow) * 32 + eoff];
        const u16* pb = &sB[cur][(wn * 64 + mrow) * 32 + eoff];
        f16x8 fa[4], fb[4];
        #pragma unroll
        for (int f = 0; f < 4; ++f) {
            fa[f] = *(const f16x8*)(pa + f * 16 * 32);
            fb[f] = *(const f16x8*)(pb + f * 16 * 32);
        }
        #pragma unroll
        for (int i = 0; i < 4; ++i) {
            #pragma unroll
            for (int j = 0; j < 4; ++j) {
                acc[i][j] = __builtin_amdgcn_mfma_f32_16x16x32_f16(fa[i], fb[j], acc[i][j], 0, 0, 0);
            }
        }
        cur = (cur == 2) ? 0 : cur + 1;
        pre = (pre == 2) ? 0 : pre + 1;
    }

    // epilogue — C/D layout: col = lane&15, row = (lane>>4)*4 + reg
    const int cq = lane & 15, rq = lane >> 4;
    if (EPI == 4) {
        #pragma unroll
        for (int i = 0; i < 4; ++i) {
            #pragma unroll
            for (int j = 0; j < 4; ++j) {
                int col = col0 + wn * 64 + j * 16 + cq;
                #pragma unroll
                for (int rr = 0; rr < 4; ++rr) {
                    int row = row0 + wm * 64 + i * 16 + rq * 4 + rr;
                    Ch[(size_t)row * HP + col] = (_Float16)acc[i][j][rr];
                }
            }
        }
    } else if (EPI == 1) {
        #pragma unroll
        for (int j = 0; j < 4; ++j) {
            int col = col0 + wn * 64 + j * 16 + cq;
            int gcol = (col0 >> 4) + wn * 4 + j;
            float bv = extra[col];
            #pragma unroll
            for (int i = 0; i < 4; ++i) {
                #pragma unroll
                for (int rr = 0; rr < 4; ++rr) {
                    float v = acc[i][j][rr] + bv;
                    v = fmaxf(v, __shfl_xor(v, 1));
                    v = fmaxf(v, __shfl_xor(v, 2));
                    v = fmaxf(v, __shfl_xor(v, 4));
                    v = fmaxf(v, __shfl_xor(v, 8));
                    if (cq == 0) {
                        int row = row0 + wm * 64 + i * 16 + rq * 4 + rr;
                        Ch[(size_t)row * H + gcol] = (_Float16)v;
                    }
                }
            }
        }
    } else {  // EPI == 3
        // 64-row wave slab [rbase, rbase+64) crosses at most one b-boundary (M=600).
        const int rbase = row0 + wm * 64;
        const int b0 = rbase / M;
        const int bnd = (b0 + 1) * M;
        #pragma unroll
        for (int j = 0; j < 4; ++j) {
            int col = col0 + wn * 64 + j * 16 + cq;
            int gcol = (col0 >> 4) + wn * 4 + j;
            float e0 = extra[(size_t)b0 * HP + col];
            float e1 = extra[(size_t)(b0 + 1) * HP + col];  // unused unless slab crosses
            #pragma unroll
            for (int i = 0; i < 4; ++i) {
                #pragma unroll
                for (int rr = 0; rr < 4; ++rr) {
                    int row = rbase + i * 16 + rq * 4 + rr;
                    float v = acc[i][j][rr] + ((row >= bnd) ? e1 : e0);
                    v = fmaxf(v, __shfl_xor(v, 1));
                    v = fmaxf(v, __shfl_xor(v, 2));
                    v = fmaxf(v, __shfl_xor(v, 4));
                    v = fmaxf(v, __shfl_xor(v, 8));
                    if (cq == 0)
                        Ch[(size_t)row * H + gcol] = (_Float16)v;
                }
            }
        }
    }
}

// ------- m1 = max16(A_f16 + rW) -> fp16 (HBM stream; used when A precomputed) -------
__global__ __launch_bounds__(256) void k_m1A16(
    const _Float16* __restrict__ A, const float* __restrict__ rW,
    _Float16* __restrict__ m1)
{
    int idx = blockIdx.x * 256 + threadIdx.x;   // bm*H + h
    int bm = idx >> 8;
    int h = idx & (H - 1);
    int b = bm / M;
    const f16x8* a8 = (const f16x8*)(A + (size_t)bm * HP + (h << 4));
    const float4* r4 = (const float4*)(rW + (size_t)b * HP + (h << 4));
    f16x8 a0 = a8[0], a1 = a8[1];
    float4 ra = r4[0], rb = r4[1], rc = r4[2], rd = r4[3];
    float mx;
    mx = fmaxf(fmaxf(fmaxf((float)a0[0] + ra.x, (float)a0[1] + ra.y),
                     fmaxf((float)a0[2] + ra.z, (float)a0[3] + ra.w)),
         fmaxf(fmaxf((float)a0[4] + rb.x, (float)a0[5] + rb.y),
               fmaxf((float)a0[6] + rb.z, (float)a0[7] + rb.w)));
    mx = fmaxf(mx,
         fmaxf(fmaxf(fmaxf((float)a1[0] + rc.x, (float)a1[1] + rc.y),
                     fmaxf((float)a1[2] + rc.z, (float)a1[3] + rc.w)),
               fmaxf(fmaxf((float)a1[4] + rd.x, (float)a1[5] + rd.y),
                     fmaxf((float)a1[6] + rd.z, (float)a1[7] + rd.w))));
    m1[idx] = (_Float16)mx;
}

// ---------------- tier 3 fp32 GEMM (round-2, known-pass) ----------------
template <int EPI>
__global__ __launch_bounds__(256) void gemm64(
    const float* __restrict__ Ag, int lda,
    const float* __restrict__ Bg, int ldb,
    const float* __restrict__ extra,
    float* __restrict__ C, int K, int ldc)
{
    __shared__ float As[16][68];
    __shared__ float Bs[16][68];
    const int tid = threadIdx.x;
    const int tx = tid & 15;
    const int ty = tid >> 4;
    const int row0 = blockIdx.y * 64;
    const int col0 = blockIdx.x * 64;
    const int lr = tid >> 2;
    const int lk = (tid & 3) << 2;
    const float* Aload = Ag + (size_t)(row0 + lr) * lda + lk;
    const float* Bload = Bg + (size_t)(col0 + lr) * ldb + lk;
    float acc[4][4] = {};
    for (int k0 = 0; k0 < K; k0 += 16) {
        float4 av = *(const float4*)(Aload + k0);
        float4 bv = *(const float4*)(Bload + k0);
        __syncthreads();
        As[lk + 0][lr] = av.x; As[lk + 1][lr] = av.y; As[lk + 2][lr] = av.z; As[lk + 3][lr] = av.w;
        Bs[lk + 0][lr] = bv.x; Bs[lk + 1][lr] = bv.y; Bs[lk + 2][lr] = bv.z; Bs[lk + 3][lr] = bv.w;
        __syncthreads();
        #pragma unroll
        for (int k = 0; k < 16; ++k) {
            float4 a4 = *(const float4*)(&As[k][ty << 2]);
            float4 b4 = *(const float4*)(&Bs[k][tx << 2]);
            acc[0][0] += a4.x * b4.x; acc[0][1] += a4.x * b4.y; acc[0][2] += a4.x * b4.z; acc[0][3] += a4.x * b4.w;
            acc[1][0] += a4.y * b4.x; acc[1][1] += a4.y * b4.y; acc[1][2] += a4.y * b4.z; acc[1][3] += a4.y * b4.w;
            acc[2][0] += a4.z * b4.x; acc[2][1] += a4.z * b4.y; acc[2][2] += a4.z * b4.z; acc[2][3] += a4.z * b4.w;
            acc[3][0] += a4.w * b4.x; acc[3][1] += a4.w * b4.y; acc[3][2] += a4.w * b4.z; acc[3][3] += a4.w * b4.w;
        }
    }
    if (EPI == 1) {
        const int cb = col0 + (tx << 2);
        float b0 = extra[cb], b1v = extra[cb + 1], b2v = extra[cb + 2], b3v = extra[cb + 3];
        #pragma unroll
        for (int i = 0; i < 4; ++i) {
            float mth = fmaxf(fmaxf(acc[i][0] + b0, acc[i][1] + b1v),
                              fmaxf(acc[i][2] + b2v, acc[i][3] + b3v));
            float r1 = fmaxf(mth, __shfl_xor(mth, 1));
            float r2 = fmaxf(r1, __shfl_xor(r1, 2));
            if ((tx & 3) == 0)
                C[(size_t)(row0 + (ty << 2) + i) * ldc + (col0 >> 4) + (tx >> 2)] = r2;
        }
    } else if (EPI == 2) {
        const int cb = col0 + (tx << 2);
        #pragma unroll
        for (int i = 0; i < 4; ++i) {
            int row = row0 + (ty << 2) + i;
            int b = row / M;
            const float* rw = extra + (size_t)b * HP + cb;
            float mth = fmaxf(fmaxf(acc[i][0] + rw[0], acc[i][1] + rw[1]),
                              fmaxf(acc[i][2] + rw[2], acc[i][3] + rw[3]));
            float r1 = fmaxf(mth, __shfl_xor(mth, 1));
            float r2 = fmaxf(r1, __shfl_xor(r1, 2));
            if ((tx & 3) == 0)
                C[(size_t)row * ldc + (col0 >> 4) + (tx >> 2)] = r2;
        }
    }
}

// ---------------- alpha (tier 3: fp32 m1) ----------------
__global__ __launch_bounds__(256) void k_alpha(
    const float* __restrict__ m1, const float* __restrict__ m2,
    const float* __restrict__ W12, const float* __restrict__ b12,
    const int* __restrict__ d_mask, float* __restrict__ alpha)
{
    __shared__ float Ws[16 * 512];
    const int tid = threadIdx.x;
    for (int i = tid; i < 16 * 512; i += 256) Ws[i] = W12[i];
    __syncthreads();
    const int wave = tid >> 6, lane = tid & 63;
    const int bm = blockIdx.x * 4 + wave;
    const float* r1 = m1 + (size_t)bm * H;
    const float* r2 = m2 + (size_t)bm * H;
    float acc[16] = {};
    #pragma unroll
    for (int q = 0; q < 4; ++q) {
        int k = lane + (q << 6);
        float x = r1[k];
        #pragma unroll
        for (int p = 0; p < 16; ++p) acc[p] += x * Ws[p * 512 + k];
    }
    #pragma unroll
    for (int q = 0; q < 4; ++q) {
        int k = lane + (q << 6);
        float x = r2[k];
        #pragma unroll
        for (int p = 0; p < 16; ++p) acc[p] += x * Ws[p * 512 + 256 + k];
    }
    #pragma unroll
    for (int p = 0; p < 16; ++p) {
        float v = acc[p];
        v += __shfl_xor(v, 1);  v += __shfl_xor(v, 2);  v += __shfl_xor(v, 4);
        v += __shfl_xor(v, 8);  v += __shfl_xor(v, 16); v += __shfl_xor(v, 32);
        acc[p] = v;
    }
    if (lane == 0) {
        float mx = -INFINITY;
        #pragma unroll
        for (int p = 0; p < 16; ++p) mx = fmaxf(mx, acc[p] + b12[p]);
        alpha[bm] = d_mask[bm] ? mx : -1e30f;
    }
}

// ------- alpha via MFMA: alpha = max_p(concat(m1,m2) @ W12h.T + b12) -------
__global__ __launch_bounds__(256) void k_alphaM(
    const _Float16* __restrict__ m1, const _Float16* __restrict__ m2,
    const _Float16* __restrict__ W12h, const float* __restrict__ b12,
    const int* __restrict__ d_mask, float* __restrict__ alpha)
{
    const int wave = threadIdx.x >> 6, lane = threadIdx.x & 63;
    const int bm0 = blockIdx.x * 64 + wave * 16;
    const int rsel = lane & 15, kg = lane >> 4;
    f16x8 fb[16];
    #pragma unroll
    for (int kb = 0; kb < 16; ++kb)
        fb[kb] = *(const f16x8*)(W12h + (size_t)rsel * 512 + kb * 32 + kg * 8);
    f32x4 acc = {};
    const _Float16* r1 = m1 + (size_t)(bm0 + rsel) * H + kg * 8;
    const _Float16* r2 = m2 + (size_t)(bm0 + rsel) * H + kg * 8;
    #pragma unroll
    for (int kb = 0; kb < 8; ++kb) {
        f16x8 fa = *(const f16x8*)(r1 + kb * 32);
        acc = __builtin_amdgcn_mfma_f32_16x16x32_f16(fa, fb[kb], acc, 0, 0, 0);
    }
    #pragma unroll
    for (int kb = 0; kb < 8; ++kb) {
        f16x8 fa = *(const f16x8*)(r2 + kb * 32);
        acc = __builtin_amdgcn_mfma_f32_16x16x32_f16(fa, fb[8 + kb], acc, 0, 0, 0);
    }
    // C/D layout: col p = lane&15, row = (lane>>4)*4 + reg
    const int cq = lane & 15, rq = lane >> 4;
    float bv = b12[cq];
    #pragma unroll
    for (int reg = 0; reg < 4; ++reg) {
        float v = acc[reg] + bv;
        v = fmaxf(v, __shfl_xor(v, 1));
        v = fmaxf(v, __shfl_xor(v, 2));
        v = fmaxf(v, __shfl_xor(v, 4));
        v = fmaxf(v, __shfl_xor(v, 8));
        if (cq == 0) {
            int bm = bm0 + rq * 4 + reg;
            alpha[bm] = d_mask[bm] ? v : -1e30f;
        }
    }
}

// ------- fused softmax + sticky-mask update: ONE block, 16 waves x 2 rows -------
__global__ __launch_bounds__(1024) void k_smu(
    const float* __restrict__ alpha, const int* __restrict__ span, int phase,
    int* __restrict__ pos, int* __restrict__ mask,
    int* __restrict__ prun, float* __restrict__ loss_vec, int t)
{
    __shared__ float s_loss[B];
    __shared__ int s_idx[B];
    const int wave = threadIdx.x >> 6, lane = threadIdx.x & 63;
    for (int b = wave; b < B; b += 16) {
        const float* row = alpha + b * M;
        float best = -INFINITY; int bidx = 0;
        for (int m = lane; m < M; m += 64) {
            float v = row[m];
            if (v > best) { best = v; bidx = m; }
        }
        #pragma unroll
        for (int off = 1; off < 64; off <<= 1) {
            float v2 = __shfl_xor(best, off);
            int i2 = __shfl_xor(bidx, off);
            if (v2 > best || (v2 == best && i2 < bidx)) { best = v2; bidx = i2; }
        }
        float ps = 0.f;
        for (int m = lane; m < M; m += 64) ps += expf(row[m] - best);
        #pragma unroll
        for (int off = 32; off > 0; off >>= 1) ps += __shfl_xor(ps, off);
        if (lane == 0) {
            float lse = best + logf(ps);
            int tgt = span[b * 2 + phase];
            s_loss[b] = -(row[tgt] - lse);
            s_idx[b] = bidx;
        }
    }
    __syncthreads();
    if (wave == 0) {
        int b = lane;
        int active = (b < B) ? 1 : 0;
        int ni = 0, nm = 0;
        if (active) {
            int id = s_idx[b];
            if (t == 0) { nm = 1; ni = id; }
            else {
                int om = mask[b];
                ni = id * om;
                int prev = pos[b] * om;
                nm = (ni != prev) ? 1 : 0;
            }
        }
        float v = active ? s_loss[b] : 0.f;
        #pragma unroll
        for (int off = 32; off > 0; off >>= 1) v += __shfl_xor(v, off);
        float S = v * (1.0f / (float)B);
        if (active) {
            pos[b] = ni;
            mask[b] = nm;
            if (nm) { prun[b] = ni; loss_vec[b] += S; }
        }
    }
}

// ---------------- per-b: argmax + logsumexp + loss term (tier-3 path) ------------
__global__ __launch_bounds__(256) void k_softmax(
    const float* __restrict__ alpha, const int* __restrict__ span, int phase,
    float* __restrict__ loss_term, int* __restrict__ idx_out)
{
    __shared__ float sv[256];
    __shared__ int si[256];
    const int b = blockIdx.x, tid = threadIdx.x;
    const float* row = alpha + b * M;
    float best = -INFINITY; int bidx = 0;
    for (int m = tid; m < M; m += 256) {
        float v = row[m];
        if (v > best) { best = v; bidx = m; }
    }
    sv[tid] = best; si[tid] = bidx;
    __syncthreads();
    for (int s = 128; s > 0; s >>= 1) {
        if (tid < s) {
            float v2 = sv[tid + s]; int i2 = si[tid + s];
            if (v2 > sv[tid] || (v2 == sv[tid] && i2 < si[tid])) { sv[tid] = v2; si[tid] = i2; }
        }
        __syncthreads();
    }
    float bmax = sv[0]; int amax = si[0];
    __syncthreads();
    float ps = 0.f;
    for (int m = tid; m < M; m += 256) ps += expf(row[m] - bmax);
    sv[tid] = ps;
    __syncthreads();
    for (int s = 128; s > 0; s >>= 1) {
        if (tid < s) sv[tid] += sv[tid + s];
        __syncthreads();
    }
    if (tid == 0) {
        float lse = bmax + logf(sv[0]);
        int tgt = span[b * 2 + phase];
        loss_term[b] = -(row[tgt] - lse);
        idx_out[b] = amax;
    }
}

// ---------------- sticky-mask pointer update + loss (tier-3 path) ----------------
__global__ void k_update(const int* __restrict__ idx_in, const float* __restrict__ loss_term,
                         int* __restrict__ pos, int* __restrict__ mask,
                         int* __restrict__ prun, float* __restrict__ loss_vec, int t)
{
    int b = threadIdx.x;
    int active = (b < B) ? 1 : 0;
    int ni = 0, nm = 0;
    if (active) {
        int id = idx_in[b];
        if (t == 0) { nm = 1; ni = id; }
        else {
            int om = mask[b];
            ni = id * om;
            int prev = pos[b] * om;
            nm = (ni != prev) ? 1 : 0;
        }
    }
    float v = active ? loss_term[b] : 0.f;
    #pragma unroll
    for (int off = 32; off > 0; off >>= 1) v += __shfl_xor(v, off);
    float S = v * (1.0f / (float)B);
    if (active) {
        pos[b] = ni;
        mask[b] = nm;
        if (nm) { prun[b] = ni; loss_vec[b] += S; }
    }
}

// ---------------- finalize ----------------
__global__ void k_finalize(const float* __restrict__ loss_vec, const int* __restrict__ p1r,
                           const int* __restrict__ p2r, float* __restrict__ out)
{
    int b = threadIdx.x;
    float v = (b < B) ? loss_vec[b] : 0.f;
    #pragma unroll
    for (int off = 32; off > 0; off >>= 1) v += __shfl_xor(v, off);
    if (b == 0) out[0] = v / (float)(B * TSTEPS);
    if (b < B) {
        out[1 + b] = (float)p1r[b];
        out[1 + B + b] = (float)p2r[b];
    }
}

}  // namespace

extern "C" void kernel_launch(void* const* d_in, const int* in_sizes, int n_in,
                              void* d_out, int out_size, void* d_ws, size_t ws_size,
                              hipStream_t stream)
{
    const float* U      = (const float*)d_in[0];
    const int*   d_mask = (const int*)d_in[1];
    const int*   span   = (const int*)d_in[2];
    const float* W_ih   = (const float*)d_in[3];
    const float* W_hh   = (const float*)d_in[4];
    const float* b_ih   = (const float*)d_in[5];
    const float* b_hh   = (const float*)d_in[6];
    const float* Ws_lin = (const float*)d_in[7];
    const float* Ws_m1  = (const float*)d_in[8];
    const float* bs_m1  = (const float*)d_in[9];
    const float* Ws_m2  = (const float*)d_in[10];
    const float* bs_m2  = (const float*)d_in[11];
    const float* Ws_m12 = (const float*)d_in[12];
    const float* bs_m12 = (const float*)d_in[13];
    const float* We_lin = (const float*)d_in[14];
    const float* We_m1  = (const float*)d_in[15];
    const float* be_m1  = (const float*)d_in[16];
    const float* We_m2  = (const float*)d_in[17];
    const float* be_m2  = (const float*)d_in[18];
    const float* We_m12 = (const float*)d_in[19];
    const float* be_m12 = (const float*)d_in[20];

    // ---- workspace layout ----
    float* ws = (float*)d_ws;
    size_t o = 0;
    float* m2b   = ws + o; o += (size_t)BM * H;
    float* alphab= ws + o; o += BM;
    float* u_cat = ws + o; o += B * FOURH;
    float* gbuf  = ws + o; o += B * FOURH;
    float* hbuf  = ws + o; o += B * H;
    float* cbuf  = ws + o; o += B * H;
    float* rbuf  = ws + o; o += B * H;
    float* rWb   = ws + o; o += B * HP;
    float* loss_term = ws + o; o += B;
    float* loss_vec  = ws + o; o += B;
    int* ib = (int*)(ws + o); o += 8 * B + 160;   // int block + 150 tile flags
    int* idxb   = ib + 0 * B;
    int* s_i    = ib + 1 * B;
    int* e_i    = ib + 2 * B;
    int* mask_s = ib + 3 * B;
    int* mask_e = ib + 4 * B;
    int* p1r    = ib + 5 * B;
    int* p2r    = ib + 6 * B;
    int* flags  = ib + 8 * B;
    size_t o_common = (o + 3) & ~(size_t)3;

    // tier 3 (fp32 fallback): m1b fp32 (aliases the fp16 region; paths exclusive)
    float* m1b = ws + o_common;

    // tiers 15/16/2: fp16 region
    _Float16* hs = (_Float16*)(ws + o_common);
    size_t q = 0;
    _Float16* Uh    = hs + q; q += (size_t)BM * TWOH;
    _Float16* W1s   = hs + q; q += (size_t)HP * TWOH;
    _Float16* W1e   = hs + q; q += (size_t)HP * TWOH;
    _Float16* W2s   = hs + q; q += (size_t)HP * H;
    _Float16* W2e   = hs + q; q += (size_t)HP * H;
    _Float16* m1b16 = hs + q; q += (size_t)BM * H;
    _Float16* Wth_s = hs + q; q += (size_t)H * HP;   // fp16 transposed rW weights
    _Float16* Wth_e = hs + q; q += (size_t)H * HP;
    _Float16* W12sh = hs + q; q += 16 * 512;
    _Float16* W12eh = hs + q; q += 16 * 512;
    q = (q + 7) & ~(size_t)7;
    const size_t need2 = o_common * sizeof(float) + q * sizeof(_Float16);
    _Float16* A_s16 = hs + q;                    // s-side iteration-invariant A (157 MB)
    _Float16* A_e16 = A_s16 + (size_t)BM * HP;   // e-side iteration-invariant A (157 MB)
    const size_t need15s = need2 + (size_t)BM * HP * sizeof(_Float16);
    const size_t need16  = need15s + (size_t)BM * HP * sizeof(_Float16);

    // m2 in fp16 for tiers != 3 (aliases the m2b region)
    _Float16* m2h = (_Float16*)m2b;

    const int tier = (ws_size >= need16) ? 16
                   : (ws_size >= need15s) ? 15
                   : (ws_size >= need2) ? 2 : 3;

    k_init<<<1, 256, 0, stream>>>(d_mask, hbuf, cbuf, loss_vec, s_i, e_i, p1r, p2r);

    if (tier != 3) {
        // rebuild every call (ws re-poisoned by harness)
        k_flags<<<NTILES, 128, 0, stream>>>(d_mask, flags);
        k_cvtH<<<BM * TWOH / 4 / 256, 256, 0, stream>>>(U, TWOH, TWOH, Uh);
        k_cvtH<<<HP * TWOH / 4 / 256, 256, 0, stream>>>(Ws_m1, THREEH, TWOH, W1s);
        k_cvtH<<<HP * TWOH / 4 / 256, 256, 0, stream>>>(We_m1, THREEH, TWOH, W1e);
        k_cvtH<<<HP * H / 4 / 256, 256, 0, stream>>>(Ws_m2, H, H, W2s);
        k_cvtH<<<HP * H / 4 / 256, 256, 0, stream>>>(We_m2, H, H, W2e);
        k_cvtH<<<16 * 512 / 4 / 256, 256, 0, stream>>>(Ws_m12, 512, 512, W12sh);
        k_cvtH<<<16 * 512 / 4 / 256, 256, 0, stream>>>(We_m12, 512, 512, W12eh);
        k_transp2<<<1024, 256, 0, stream>>>(Ws_m1, Wth_s);
        k_transp2<<<1024, 256, 0, stream>>>(We_m1, Wth_e);

        dim3 gJ(HP / 128, NTILES);  // (32, 150)
        if (tier >= 15) {
            // iteration-invariant A_s = U @ Ws_m1[:, :512].T, fp16 (157 MB).
            gemmJ<4><<<gJ, 256, 0, stream>>>(Uh, W1s, TWOH, nullptr, flags, nullptr, A_s16);
        }
        if (tier == 16) {
            gemmJ<4><<<gJ, 256, 0, stream>>>(Uh, W1e, TWOH, nullptr, flags, nullptr, A_e16);
        }

        for (int t = 0; t < TSTEPS; ++t) {
            k_lstm_gemm2<<<128, 256, 0, stream>>>(U, s_i, e_i, hbuf, W_ih, W_hh, b_ih, b_hh, gbuf);
            k_lstm_gates<<<32, 256, 0, stream>>>(gbuf, hbuf, cbuf);

            // ---- start pointer ----
            k_r2<<<128, 256, 0, stream>>>(hbuf, U, s_i, e_i, Ws_lin, rbuf);
            k_rW2h<<<dim3(HP / 512, B), 256, 0, stream>>>(rbuf, Wth_s, bs_m1, rWb);
            if (tier >= 15)
                k_m1A16<<<BM * H / 256, 256, 0, stream>>>(A_s16, rWb, m1b16);
            else
                gemmJ<3><<<gJ, 256, 0, stream>>>(Uh, W1s, TWOH, rWb, flags, nullptr, m1b16);
            gemmJ<1><<<gJ, 256, 0, stream>>>(m1b16, W2s, H, bs_m2, flags, nullptr, m2h);
            k_alphaM<<<BM / 64, 256, 0, stream>>>(m1b16, m2h, W12sh, bs_m12, d_mask, alphab);
            k_smu<<<1, 1024, 0, stream>>>(alphab, span, 0, s_i, mask_s, p1r, loss_vec, t);

            // ---- end pointer (s_i now updated; direct U reads pick it up) ----
            k_r2<<<128, 256, 0, stream>>>(hbuf, U, s_i, e_i, We_lin, rbuf);
            k_rW2h<<<dim3(HP / 512, B), 256, 0, stream>>>(rbuf, Wth_e, be_m1, rWb);
            if (tier == 16)
                k_m1A16<<<BM * H / 256, 256, 0, stream>>>(A_e16, rWb, m1b16);
            else
                gemmJ<3><<<gJ, 256, 0, stream>>>(Uh, W1e, TWOH, rWb, flags, nullptr, m1b16);
            gemmJ<1><<<gJ, 256, 0, stream>>>(m1b16, W2e, H, be_m2, flags, nullptr, m2h);
            k_alphaM<<<BM / 64, 256, 0, stream>>>(m1b16, m2h, W12eh, be_m12, d_mask, alphab);
            k_smu<<<1, 1024, 0, stream>>>(alphab, span, 1, e_i, mask_e, p2r, loss_vec, t);
        }
    } else {
        // ---- tier 3: round-2 fp32 path (known-pass) ----
        dim3 gemm_grid(HP / 64, BM / 64);
        for (int t = 0; t < TSTEPS; ++t) {
            k_gather<<<64, 256, 0, stream>>>(U, s_i, e_i, u_cat);
            k_lstm_gemm<<<128, 256, 0, stream>>>(u_cat, hbuf, W_ih, W_hh, b_ih, b_hh, gbuf);
            k_lstm_gates<<<32, 256, 0, stream>>>(gbuf, hbuf, cbuf);

            k_r<<<32, 256, 0, stream>>>(hbuf, u_cat, Ws_lin, rbuf);
            k_rW<<<512, 256, 0, stream>>>(rbuf, Ws_m1, bs_m1, rWb);
            gemm64<2><<<gemm_grid, 256, 0, stream>>>(U, TWOH, Ws_m1, THREEH, rWb, m1b, TWOH, H);
            gemm64<1><<<gemm_grid, 256, 0, stream>>>(m1b, H, Ws_m2, H, bs_m2, m2b, H, H);
            k_alpha<<<BM / 4, 256, 0, stream>>>(m1b, m2b, Ws_m12, bs_m12, d_mask, alphab);
            k_softmax<<<B, 256, 0, stream>>>(alphab, span, 0, loss_term, idxb);
            k_update<<<1, 64, 0, stream>>>(idxb, loss_term, s_i, mask_s, p1r, loss_vec, t);

            k_gather<<<64, 256, 0, stream>>>(U, s_i, e_i, u_cat);

            k_r<<<32, 256, 0, stream>>>(hbuf, u_cat, We_lin, rbuf);
            k_rW<<<512, 256, 0, stream>>>(rbuf, We_m1, be_m1, rWb);
            gemm64<2><<<gemm_grid, 256, 0, stream>>>(U, TWOH, We_m1, THREEH, rWb, m1b, TWOH, H);
            gemm64<1><<<gemm_grid, 256, 0, stream>>>(m1b, H, We_m2, H, be_m2, m2b, H, H);
            k_alpha<<<BM / 4, 256, 0, stream>>>(m1b, m2b, We_m12, be_m12, d_mask, alphab);
            k_softmax<<<B, 256, 0, stream>>>(alphab, span, 1, loss_term, idxb);
            k_update<<<1, 64, 0, stream>>>(idxb, loss_term, e_i, mask_e, p2r, loss_vec, t);
        }
    }

    k_finalize<<<1, 64, 0, stream>>>(loss_vec, p1r, p2r, (float*)d_out);
}

// Round 10
// 2385.185 us; speedup vs baseline: 1.0665x; 1.0665x over previous
//
#include <hip/hip_runtime.h>
#include <math.h>

namespace {

typedef unsigned short u16;
typedef __attribute__((ext_vector_type(4))) float f32x4;
typedef __attribute__((ext_vector_type(8))) _Float16 f16x8;
typedef __attribute__((ext_vector_type(4))) _Float16 f16x4;
typedef __attribute__((ext_vector_type(2))) _Float16 f16x2;

constexpr int B = 32;
constexpr int M = 600;
constexpr int H = 256;
constexpr int TSTEPS = 4;
constexpr int HP = 4096;          // H*P
constexpr int BM = B * M;         // 19200
constexpr int TWOH = 512;
constexpr int THREEH = 768;
constexpr int FOURH = 1024;
constexpr int FIVEH = 1280;
constexpr int NTILES = BM / 128;  // 150 row tiles (128-row granularity — r5 winner)

__device__ __forceinline__ float sigf(float x) { return 1.0f / (1.0f + expf(-x)); }

__device__ __forceinline__ void gload16(const u16* g, u16* l) {
    __builtin_amdgcn_global_load_lds(
        (const __attribute__((address_space(1))) void*)g,
        (__attribute__((address_space(3))) void*)l, 16, 0, 0);
}

// ---------------- init ----------------
__global__ void k_init(const int* __restrict__ d_mask,
                       float* __restrict__ h, float* __restrict__ c,
                       float* __restrict__ loss_vec,
                       int* __restrict__ s_i, int* __restrict__ e_i,
                       int* __restrict__ p1r, int* __restrict__ p2r)
{
    int tid = threadIdx.x;
    for (int i = tid; i < B * H; i += 256) { h[i] = 0.f; c[i] = 0.f; }
    if (tid < B) {
        loss_vec[tid] = 0.f;
        s_i[tid] = 0;
        int s = 0;
        const int* row = d_mask + tid * M;
        for (int m = 0; m < M; ++m) s += row[m];
        e_i[tid] = s - 1;
        p1r[tid] = 0; p2r[tid] = 0;
    }
}

// ---------------- per-128-row-tile skip flags (1 = fully masked) ----------------
__global__ __launch_bounds__(128) void k_flags(const int* __restrict__ d_mask,
                                               int* __restrict__ flags)
{
    int bm = blockIdx.x * 128 + threadIdx.x;
    int cnt = __syncthreads_count(d_mask[bm]);
    if (threadIdx.x == 0) flags[blockIdx.x] = (cnt == 0) ? 1 : 0;
}

// ---------------- gather u_cat = [U[b, s_i], U[b, e_i]] (tier-3 path only) -------
__global__ __launch_bounds__(256) void k_gather(
    const float* __restrict__ U, const int* __restrict__ s_i,
    const int* __restrict__ e_i, float* __restrict__ u_cat)
{
    int idx = blockIdx.x * 256 + threadIdx.x;   // B*512 threads
    int b = idx >> 9, k = idx & 511;
    u_cat[b * FOURH + k]       = U[((size_t)b * M + s_i[b]) * TWOH + k];
    u_cat[b * FOURH + 512 + k] = U[((size_t)b * M + e_i[b]) * TWOH + k];
}

// ---------------- LSTM gemm, u_cat read directly from U via indices ----------------
__global__ __launch_bounds__(256) void k_lstm_gemm2(
    const float* __restrict__ U, const int* __restrict__ s_i,
    const int* __restrict__ e_i, const float* __restrict__ h,
    const float* __restrict__ W_ih, const float* __restrict__ W_hh,
    const float* __restrict__ b_ih, const float* __restrict__ b_hh,
    float* __restrict__ g)
{
    int idx = blockIdx.x * 256 + threadIdx.x;   // B*1024 threads
    int b = idx >> 10, j = idx & 1023;
    const float* us = U + ((size_t)b * M + s_i[b]) * TWOH;
    const float* ue = U + ((size_t)b * M + e_i[b]) * TWOH;
    float acc = 0.f;
    const float4* x4 = (const float4*)us;
    const float4* wi4 = (const float4*)(W_ih + (size_t)j * FOURH);
    #pragma unroll 4
    for (int k = 0; k < TWOH / 4; ++k) {
        float4 a = x4[k], w = wi4[k];
        acc += a.x * w.x + a.y * w.y + a.z * w.z + a.w * w.w;
    }
    const float4* y4 = (const float4*)ue;
    const float4* wi4b = wi4 + TWOH / 4;
    #pragma unroll 4
    for (int k = 0; k < TWOH / 4; ++k) {
        float4 a = y4[k], w = wi4b[k];
        acc += a.x * w.x + a.y * w.y + a.z * w.z + a.w * w.w;
    }
    const float4* h4 = (const float4*)(h + b * H);
    const float4* wh4 = (const float4*)(W_hh + (size_t)j * H);
    #pragma unroll 4
    for (int k = 0; k < H / 4; ++k) {
        float4 a = h4[k], w = wh4[k];
        acc += a.x * w.x + a.y * w.y + a.z * w.z + a.w * w.w;
    }
    g[idx] = acc + b_ih[j] + b_hh[j];
}

// (tier-3 fallback keeps old u_cat-based version)
__global__ __launch_bounds__(256) void k_lstm_gemm(
    const float* __restrict__ u_cat, const float* __restrict__ h,
    const float* __restrict__ W_ih, const float* __restrict__ W_hh,
    const float* __restrict__ b_ih, const float* __restrict__ b_hh,
    float* __restrict__ g)
{
    int idx = blockIdx.x * 256 + threadIdx.x;   // B*1024 threads
    int b = idx >> 10, j = idx & 1023;
    float acc = 0.f;
    const float4* x4 = (const float4*)(u_cat + b * FOURH);
    const float4* wi4 = (const float4*)(W_ih + (size_t)j * FOURH);
    #pragma unroll 4
    for (int k = 0; k < FOURH / 4; ++k) {
        float4 a = x4[k], w = wi4[k];
        acc += a.x * w.x + a.y * w.y + a.z * w.z + a.w * w.w;
    }
    const float4* h4 = (const float4*)(h + b * H);
    const float4* wh4 = (const float4*)(W_hh + (size_t)j * H);
    #pragma unroll 4
    for (int k = 0; k < H / 4; ++k) {
        float4 a = h4[k], w = wh4[k];
        acc += a.x * w.x + a.y * w.y + a.z * w.z + a.w * w.w;
    }
    g[idx] = acc + b_ih[j] + b_hh[j];
}

__global__ __launch_bounds__(256) void k_lstm_gates(
    const float* __restrict__ g, float* __restrict__ h, float* __restrict__ c)
{
    int idx = blockIdx.x * 256 + threadIdx.x;   // B*H
    int b = idx >> 8, i = idx & (H - 1);
    const float* gr = g + b * FOURH;
    float gi = gr[i], gf = gr[H + i], gg = gr[2 * H + i], go = gr[3 * H + i];
    float cn = sigf(gf) * c[idx] + sigf(gi) * tanhf(gg);
    c[idx] = cn;
    h[idx] = sigf(go) * tanhf(cn);
}

// ------- r = tanh([h | U[b,s_i] | U[b,e_i]] @ W_lin.T), 4-way K-split -------
__global__ __launch_bounds__(256) void k_r2(
    const float* __restrict__ h, const float* __restrict__ U,
    const int* __restrict__ s_i, const int* __restrict__ e_i,
    const float* __restrict__ W_lin, float* __restrict__ r)
{
    int gid = blockIdx.x * 256 + threadIdx.x;   // B*H*4 threads (128 blocks)
    int out = gid >> 2;
    int part = gid & 3;
    int b = out >> 8, i = out & (H - 1);
    const float4* w4 = (const float4*)(W_lin + (size_t)i * FIVEH);
    const float4* h4 = (const float4*)(h + b * H);
    const float4* us4 = (const float4*)(U + ((size_t)b * M + s_i[b]) * TWOH);
    const float4* ue4 = (const float4*)(U + ((size_t)b * M + e_i[b]) * TWOH);
    // concat layout in float4 units: h [0,64), u_s [64,192), u_e [192,320)
    float acc = 0.f;
    int k0 = part * 80;
    #pragma unroll 4
    for (int kk = k0; kk < k0 + 80; ++kk) {
        float4 a;
        if (kk < 64) a = h4[kk];
        else if (kk < 192) a = us4[kk - 64];
        else a = ue4[kk - 192];
        float4 ww = w4[kk];
        acc += a.x * ww.x + a.y * ww.y + a.z * ww.z + a.w * ww.w;
    }
    acc += __shfl_xor(acc, 1);
    acc += __shfl_xor(acc, 2);
    if (part == 0) r[out] = tanhf(acc);
}

// (tier-3 fallback keeps old u_cat-based version)
__global__ __launch_bounds__(256) void k_r(
    const float* __restrict__ h, const float* __restrict__ u_cat,
    const float* __restrict__ W_lin, float* __restrict__ r)
{
    int idx = blockIdx.x * 256 + threadIdx.x;   // B*H
    int b = idx >> 8, i = idx & (H - 1);
    const float* w = W_lin + (size_t)i * FIVEH;
    float acc = 0.f;
    const float4* h4 = (const float4*)(h + b * H);
    const float4* w4 = (const float4*)w;
    #pragma unroll 4
    for (int k = 0; k < H / 4; ++k) {
        float4 a = h4[k], ww = w4[k];
        acc += a.x * ww.x + a.y * ww.y + a.z * ww.z + a.w * ww.w;
    }
    const float4* x4 = (const float4*)(u_cat + b * FOURH);
    const float4* w4b = (const float4*)(w + H);
    #pragma unroll 4
    for (int k = 0; k < FOURH / 4; ++k) {
        float4 a = x4[k], ww = w4b[k];
        acc += a.x * ww.x + a.y * ww.y + a.z * ww.z + a.w * ww.w;
    }
    r[idx] = tanhf(acc);
}

// ---------------- old strided rW (tier 3) ----------------
__global__ __launch_bounds__(256) void k_rW(
    const float* __restrict__ r, const float* __restrict__ W1,
    const float* __restrict__ b1, float* __restrict__ rW)
{
    int idx = blockIdx.x * 256 + threadIdx.x;   // B*HP
    int b = idx >> 12, j = idx & (HP - 1);
    const float4* r4 = (const float4*)(r + b * H);
    const float4* w4 = (const float4*)(W1 + (size_t)j * THREEH + TWOH);
    float acc = 0.f;
    #pragma unroll 4
    for (int k = 0; k < H / 4; ++k) {
        float4 a = r4[k], w = w4[k];
        acc += a.x * w.x + a.y * w.y + a.z * w.z + a.w * w.w;
    }
    rW[idx] = acc + b1[j];
}

// ------- coalesced rW via fp16 transposed weight, 2 cols/thread -------
__global__ __launch_bounds__(256) void k_rW2h(
    const float* __restrict__ r, const _Float16* __restrict__ Wt,
    const float* __restrict__ b1, float* __restrict__ rW)
{
    const int b = blockIdx.y;
    const int j = (blockIdx.x * 256 + threadIdx.x) * 2;
    __shared__ float sr[256];
    sr[threadIdx.x] = r[b * H + threadIdx.x];
    __syncthreads();
    float a0 = b1[j], a1 = b1[j + 1];
    #pragma unroll 4
    for (int k = 0; k < H; ++k) {
        f16x2 wv = *(const f16x2*)(Wt + (size_t)k * HP + j);
        float x = sr[k];
        a0 += x * (float)wv[0];
        a1 += x * (float)wv[1];
    }
    rW[(size_t)b * HP + j]     = a0;
    rW[(size_t)b * HP + j + 1] = a1;
}

// ------- LDS-tiled transpose W1[:, 512:768] -> fp16 Wt[256][4096] -------
__global__ __launch_bounds__(256) void k_transp2(
    const float* __restrict__ W, _Float16* __restrict__ Wt)
{
    __shared__ float s[32][33];
    int j0 = (blockIdx.x & 127) << 5;           // 128 j-tiles
    int k0 = (blockIdx.x >> 7) << 5;            // 8 k-tiles
    int tx = threadIdx.x & 31, ty = threadIdx.x >> 5;
    #pragma unroll
    for (int kk = 0; kk < 4; ++kk) {
        int jl = ty + kk * 8;
        s[jl][tx] = W[(size_t)(j0 + jl) * THREEH + TWOH + k0 + tx];
    }
    __syncthreads();
    #pragma unroll
    for (int kk = 0; kk < 4; ++kk) {
        int kl = ty + kk * 8;
        Wt[(size_t)(k0 + kl) * HP + j0 + tx] = (_Float16)s[tx][kl];
    }
}

// ---------------- fp32 -> fp16 converter ----------------
__global__ __launch_bounds__(256) void k_cvtH(
    const float* __restrict__ src, int ld, int Kc, _Float16* __restrict__ dst)
{
    int i4 = blockIdx.x * 256 + threadIdx.x;    // over N*Kc/4
    int perrow = Kc >> 2;
    int row = i4 / perrow;
    int kc = (i4 - row * perrow) << 2;
    float4 v = *(const float4*)(src + (size_t)row * ld + kc);
    f16x4 o;
    o[0] = (_Float16)v.x; o[1] = (_Float16)v.y; o[2] = (_Float16)v.z; o[3] = (_Float16)v.w;
    *(f16x4*)(dst + (size_t)row * Kc + kc) = o;
}

// ---- fp16 MFMA GEMM: 128x128 tile, BK=32, 256 threads (2x2 waves of 64x64) ----
// FINAL config (r8, best verified 2415.7us): r5 winner + XCD swizzle.
// Structural attempts that FAILED and are knowingly excluded: 256^2 tile (r1/2,
// occupancy loss), 256x128 wave-tile (r6, latency-bound regression), 3-buffer
// counted-vmcnt pipeline (r9: +24 VGPR, -8pt occupancy, +22MB FETCH, +14us).
// The 2-buffer issue-after-barrier loop already covers staging latency with one
// full iteration of all-wave compute; ~21% MfmaUtil is this structure's local
// optimum at K=512.
// skip[tile]=1 -> fully-masked row tile, early exit.
// EPI=1: +bias[col], max over 16-col groups -> Ch fp16 [rows x 256]      (m2)
// EPI=3: +rW[row/M][col], max over 16-col groups -> Ch fp16 [rows x 256] (m1)
// EPI=4: plain store fp16 C [rows x 4096] into Ch                        (precompute)
template <int EPI>
__global__ __launch_bounds__(256, 4) void gemmJ(
    const _Float16* __restrict__ A, const _Float16* __restrict__ Bw,
    int K, const float* __restrict__ extra, const int* __restrict__ skip,
    float* __restrict__ Cf, _Float16* __restrict__ Ch)
{
    // ---- XCD swizzle (time-neutral, fixes 3.4x write amplification) ----
    const int nwgx = gridDim.x;                  // 32
    const int nwg  = nwgx * gridDim.y;           // 4800 (mult of 8)
    int bid = blockIdx.y * nwgx + blockIdx.x;
    const int cpx = nwg >> 3;
    bid = (bid & 7) * cpx + (bid >> 3);
    const int bx = bid % nwgx, by = bid / nwgx;

    if (skip[by]) return;
    __shared__ __align__(16) u16 sA[2][128 * 32];
    __shared__ __align__(16) u16 sB[2][128 * 32];
    const int tid = threadIdx.x;
    const int w = tid >> 6, lane = tid & 63;
    const int row0 = by * 128, col0 = bx * 128;
    const int wm = w & 1, wn = w >> 1;          // 2x2 wave grid, 64x64 each

    const int r1g = tid >> 2,        k1 = (tid & 3) ^ ((r1g >> 1) & 3);
    const int r2g = (tid + 256) >> 2, k2 = ((tid + 256) & 3) ^ ((r2g >> 1) & 3);
    const size_t gA1 = (size_t)(row0 + r1g) * K + k1 * 8;
    const size_t gA2 = (size_t)(row0 + r2g) * K + k2 * 8;
    const size_t gB1 = (size_t)(col0 + r1g) * K + k1 * 8;
    const size_t gB2 = (size_t)(col0 + r2g) * K + k2 * 8;

    f32x4 acc[4][4] = {};

    gload16((const u16*)(A  + gA1), &sA[0][tid * 8]);
    gload16((const u16*)(A  + gA2), &sA[0][(tid + 256) * 8]);
    gload16((const u16*)(Bw + gB1), &sB[0][tid * 8]);
    gload16((const u16*)(Bw + gB2), &sB[0][(tid + 256) * 8]);

    const int iters = K >> 5;
    const int mrow = lane & 15;
    const int kg = lane >> 4;
    const int slot = kg ^ ((mrow >> 1) & 3);
    const int eoff = slot << 3;

    for (int it = 0; it < iters; ++it) {
        const int cur = it & 1;
        __syncthreads();
        if (it + 1 < iters) {
            const int k0n = (it + 1) << 5;
            gload16((const u16*)(A  + gA1 + k0n), &sA[1 - cur][tid * 8]);
            gload16((const u16*)(A  + gA2 + k0n), &sA[1 - cur][(tid + 256) * 8]);
            gload16((const u16*)(Bw + gB1 + k0n), &sB[1 - cur][tid * 8]);
            gload16((const u16*)(Bw + gB2 + k0n), &sB[1 - cur][(tid + 256) * 8]);
        }
        const u16* pa = &sA[cur][(wm * 64 + mrow) * 32 + eoff];
        const u16* pb = &sB[cur][(wn * 64 + mrow) * 32 + eoff];
        f16x8 fa[4], fb[4];
        #pragma unroll
        for (int f = 0; f < 4; ++f) {
            fa[f] = *(const f16x8*)(pa + f * 16 * 32);
            fb[f] = *(const f16x8*)(pb + f * 16 * 32);
        }
        #pragma unroll
        for (int i = 0; i < 4; ++i) {
            #pragma unroll
            for (int j = 0; j < 4; ++j) {
                acc[i][j] = __builtin_amdgcn_mfma_f32_16x16x32_f16(fa[i], fb[j], acc[i][j], 0, 0, 0);
            }
        }
    }

    // epilogue — C/D layout: col = lane&15, row = (lane>>4)*4 + reg
    const int cq = lane & 15, rq = lane >> 4;
    if (EPI == 4) {
        #pragma unroll
        for (int i = 0; i < 4; ++i) {
            #pragma unroll
            for (int j = 0; j < 4; ++j) {
                int col = col0 + wn * 64 + j * 16 + cq;
                #pragma unroll
                for (int rr = 0; rr < 4; ++rr) {
                    int row = row0 + wm * 64 + i * 16 + rq * 4 + rr;
                    Ch[(size_t)row * HP + col] = (_Float16)acc[i][j][rr];
                }
            }
        }
    } else if (EPI == 1) {
        #pragma unroll
        for (int j = 0; j < 4; ++j) {
            int col = col0 + wn * 64 + j * 16 + cq;
            int gcol = (col0 >> 4) + wn * 4 + j;
            float bv = extra[col];
            #pragma unroll
            for (int i = 0; i < 4; ++i) {
                #pragma unroll
                for (int rr = 0; rr < 4; ++rr) {
                    float v = acc[i][j][rr] + bv;
                    v = fmaxf(v, __shfl_xor(v, 1));
                    v = fmaxf(v, __shfl_xor(v, 2));
                    v = fmaxf(v, __shfl_xor(v, 4));
                    v = fmaxf(v, __shfl_xor(v, 8));
                    if (cq == 0) {
                        int row = row0 + wm * 64 + i * 16 + rq * 4 + rr;
                        Ch[(size_t)row * H + gcol] = (_Float16)v;
                    }
                }
            }
        }
    } else {  // EPI == 3
        // 64-row wave slab [rbase, rbase+64) crosses at most one b-boundary (M=600).
        const int rbase = row0 + wm * 64;
        const int b0 = rbase / M;
        const int bnd = (b0 + 1) * M;
        #pragma unroll
        for (int j = 0; j < 4; ++j) {
            int col = col0 + wn * 64 + j * 16 + cq;
            int gcol = (col0 >> 4) + wn * 4 + j;
            float e0 = extra[(size_t)b0 * HP + col];
            float e1 = extra[(size_t)(b0 + 1) * HP + col];  // unused unless slab crosses
            #pragma unroll
            for (int i = 0; i < 4; ++i) {
                #pragma unroll
                for (int rr = 0; rr < 4; ++rr) {
                    int row = rbase + i * 16 + rq * 4 + rr;
                    float v = acc[i][j][rr] + ((row >= bnd) ? e1 : e0);
                    v = fmaxf(v, __shfl_xor(v, 1));
                    v = fmaxf(v, __shfl_xor(v, 2));
                    v = fmaxf(v, __shfl_xor(v, 4));
                    v = fmaxf(v, __shfl_xor(v, 8));
                    if (cq == 0)
                        Ch[(size_t)row * H + gcol] = (_Float16)v;
                }
            }
        }
    }
}

// ------- m1 = max16(A_f16 + rW) -> fp16 (HBM stream; used when A precomputed) -------
__global__ __launch_bounds__(256) void k_m1A16(
    const _Float16* __restrict__ A, const float* __restrict__ rW,
    _Float16* __restrict__ m1)
{
    int idx = blockIdx.x * 256 + threadIdx.x;   // bm*H + h
    int bm = idx >> 8;
    int h = idx & (H - 1);
    int b = bm / M;
    const f16x8* a8 = (const f16x8*)(A + (size_t)bm * HP + (h << 4));
    const float4* r4 = (const float4*)(rW + (size_t)b * HP + (h << 4));
    f16x8 a0 = a8[0], a1 = a8[1];
    float4 ra = r4[0], rb = r4[1], rc = r4[2], rd = r4[3];
    float mx;
    mx = fmaxf(fmaxf(fmaxf((float)a0[0] + ra.x, (float)a0[1] + ra.y),
                     fmaxf((float)a0[2] + ra.z, (float)a0[3] + ra.w)),
         fmaxf(fmaxf((float)a0[4] + rb.x, (float)a0[5] + rb.y),
               fmaxf((float)a0[6] + rb.z, (float)a0[7] + rb.w)));
    mx = fmaxf(mx,
         fmaxf(fmaxf(fmaxf((float)a1[0] + rc.x, (float)a1[1] + rc.y),
                     fmaxf((float)a1[2] + rc.z, (float)a1[3] + rc.w)),
               fmaxf(fmaxf((float)a1[4] + rd.x, (float)a1[5] + rd.y),
                     fmaxf((float)a1[6] + rd.z, (float)a1[7] + rd.w))));
    m1[idx] = (_Float16)mx;
}

// ---------------- tier 3 fp32 GEMM (round-2, known-pass) ----------------
template <int EPI>
__global__ __launch_bounds__(256) void gemm64(
    const float* __restrict__ Ag, int lda,
    const float* __restrict__ Bg, int ldb,
    const float* __restrict__ extra,
    float* __restrict__ C, int K, int ldc)
{
    __shared__ float As[16][68];
    __shared__ float Bs[16][68];
    const int tid = threadIdx.x;
    const int tx = tid & 15;
    const int ty = tid >> 4;
    const int row0 = blockIdx.y * 64;
    const int col0 = blockIdx.x * 64;
    const int lr = tid >> 2;
    const int lk = (tid & 3) << 2;
    const float* Aload = Ag + (size_t)(row0 + lr) * lda + lk;
    const float* Bload = Bg + (size_t)(col0 + lr) * ldb + lk;
    float acc[4][4] = {};
    for (int k0 = 0; k0 < K; k0 += 16) {
        float4 av = *(const float4*)(Aload + k0);
        float4 bv = *(const float4*)(Bload + k0);
        __syncthreads();
        As[lk + 0][lr] = av.x; As[lk + 1][lr] = av.y; As[lk + 2][lr] = av.z; As[lk + 3][lr] = av.w;
        Bs[lk + 0][lr] = bv.x; Bs[lk + 1][lr] = bv.y; Bs[lk + 2][lr] = bv.z; Bs[lk + 3][lr] = bv.w;
        __syncthreads();
        #pragma unroll
        for (int k = 0; k < 16; ++k) {
            float4 a4 = *(const float4*)(&As[k][ty << 2]);
            float4 b4 = *(const float4*)(&Bs[k][tx << 2]);
            acc[0][0] += a4.x * b4.x; acc[0][1] += a4.x * b4.y; acc[0][2] += a4.x * b4.z; acc[0][3] += a4.x * b4.w;
            acc[1][0] += a4.y * b4.x; acc[1][1] += a4.y * b4.y; acc[1][2] += a4.y * b4.z; acc[1][3] += a4.y * b4.w;
            acc[2][0] += a4.z * b4.x; acc[2][1] += a4.z * b4.y; acc[2][2] += a4.z * b4.z; acc[2][3] += a4.z * b4.w;
            acc[3][0] += a4.w * b4.x; acc[3][1] += a4.w * b4.y; acc[3][2] += a4.w * b4.z; acc[3][3] += a4.w * b4.w;
        }
    }
    if (EPI == 1) {
        const int cb = col0 + (tx << 2);
        float b0 = extra[cb], b1v = extra[cb + 1], b2v = extra[cb + 2], b3v = extra[cb + 3];
        #pragma unroll
        for (int i = 0; i < 4; ++i) {
            float mth = fmaxf(fmaxf(acc[i][0] + b0, acc[i][1] + b1v),
                              fmaxf(acc[i][2] + b2v, acc[i][3] + b3v));
            float r1 = fmaxf(mth, __shfl_xor(mth, 1));
            float r2 = fmaxf(r1, __shfl_xor(r1, 2));
            if ((tx & 3) == 0)
                C[(size_t)(row0 + (ty << 2) + i) * ldc + (col0 >> 4) + (tx >> 2)] = r2;
        }
    } else if (EPI == 2) {
        const int cb = col0 + (tx << 2);
        #pragma unroll
        for (int i = 0; i < 4; ++i) {
            int row = row0 + (ty << 2) + i;
            int b = row / M;
            const float* rw = extra + (size_t)b * HP + cb;
            float mth = fmaxf(fmaxf(acc[i][0] + rw[0], acc[i][1] + rw[1]),
                              fmaxf(acc[i][2] + rw[2], acc[i][3] + rw[3]));
            float r1 = fmaxf(mth, __shfl_xor(mth, 1));
            float r2 = fmaxf(r1, __shfl_xor(r1, 2));
            if ((tx & 3) == 0)
                C[(size_t)row * ldc + (col0 >> 4) + (tx >> 2)] = r2;
        }
    }
}

// ---------------- alpha (tier 3: fp32 m1) ----------------
__global__ __launch_bounds__(256) void k_alpha(
    const float* __restrict__ m1, const float* __restrict__ m2,
    const float* __restrict__ W12, const float* __restrict__ b12,
    const int* __restrict__ d_mask, float* __restrict__ alpha)
{
    __shared__ float Ws[16 * 512];
    const int tid = threadIdx.x;
    for (int i = tid; i < 16 * 512; i += 256) Ws[i] = W12[i];
    __syncthreads();
    const int wave = tid >> 6, lane = tid & 63;
    const int bm = blockIdx.x * 4 + wave;
    const float* r1 = m1 + (size_t)bm * H;
    const float* r2 = m2 + (size_t)bm * H;
    float acc[16] = {};
    #pragma unroll
    for (int q = 0; q < 4; ++q) {
        int k = lane + (q << 6);
        float x = r1[k];
        #pragma unroll
        for (int p = 0; p < 16; ++p) acc[p] += x * Ws[p * 512 + k];
    }
    #pragma unroll
    for (int q = 0; q < 4; ++q) {
        int k = lane + (q << 6);
        float x = r2[k];
        #pragma unroll
        for (int p = 0; p < 16; ++p) acc[p] += x * Ws[p * 512 + 256 + k];
    }
    #pragma unroll
    for (int p = 0; p < 16; ++p) {
        float v = acc[p];
        v += __shfl_xor(v, 1);  v += __shfl_xor(v, 2);  v += __shfl_xor(v, 4);
        v += __shfl_xor(v, 8);  v += __shfl_xor(v, 16); v += __shfl_xor(v, 32);
        acc[p] = v;
    }
    if (lane == 0) {
        float mx = -INFINITY;
        #pragma unroll
        for (int p = 0; p < 16; ++p) mx = fmaxf(mx, acc[p] + b12[p]);
        alpha[bm] = d_mask[bm] ? mx : -1e30f;
    }
}

// ------- alpha via MFMA: alpha = max_p(concat(m1,m2) @ W12h.T + b12) -------
__global__ __launch_bounds__(256) void k_alphaM(
    const _Float16* __restrict__ m1, const _Float16* __restrict__ m2,
    const _Float16* __restrict__ W12h, const float* __restrict__ b12,
    const int* __restrict__ d_mask, float* __restrict__ alpha)
{
    const int wave = threadIdx.x >> 6, lane = threadIdx.x & 63;
    const int bm0 = blockIdx.x * 64 + wave * 16;
    const int rsel = lane & 15, kg = lane >> 4;
    f16x8 fb[16];
    #pragma unroll
    for (int kb = 0; kb < 16; ++kb)
        fb[kb] = *(const f16x8*)(W12h + (size_t)rsel * 512 + kb * 32 + kg * 8);
    f32x4 acc = {};
    const _Float16* r1 = m1 + (size_t)(bm0 + rsel) * H + kg * 8;
    const _Float16* r2 = m2 + (size_t)(bm0 + rsel) * H + kg * 8;
    #pragma unroll
    for (int kb = 0; kb < 8; ++kb) {
        f16x8 fa = *(const f16x8*)(r1 + kb * 32);
        acc = __builtin_amdgcn_mfma_f32_16x16x32_f16(fa, fb[kb], acc, 0, 0, 0);
    }
    #pragma unroll
    for (int kb = 0; kb < 8; ++kb) {
        f16x8 fa = *(const f16x8*)(r2 + kb * 32);
        acc = __builtin_amdgcn_mfma_f32_16x16x32_f16(fa, fb[8 + kb], acc, 0, 0, 0);
    }
    // C/D layout: col p = lane&15, row = (lane>>4)*4 + reg
    const int cq = lane & 15, rq = lane >> 4;
    float bv = b12[cq];
    #pragma unroll
    for (int reg = 0; reg < 4; ++reg) {
        float v = acc[reg] + bv;
        v = fmaxf(v, __shfl_xor(v, 1));
        v = fmaxf(v, __shfl_xor(v, 2));
        v = fmaxf(v, __shfl_xor(v, 4));
        v = fmaxf(v, __shfl_xor(v, 8));
        if (cq == 0) {
            int bm = bm0 + rq * 4 + reg;
            alpha[bm] = d_mask[bm] ? v : -1e30f;
        }
    }
}

// ------- fused softmax + sticky-mask update: ONE block, 16 waves x 2 rows -------
__global__ __launch_bounds__(1024) void k_smu(
    const float* __restrict__ alpha, const int* __restrict__ span, int phase,
    int* __restrict__ pos, int* __restrict__ mask,
    int* __restrict__ prun, float* __restrict__ loss_vec, int t)
{
    __shared__ float s_loss[B];
    __shared__ int s_idx[B];
    const int wave = threadIdx.x >> 6, lane = threadIdx.x & 63;
    for (int b = wave; b < B; b += 16) {
        const float* row = alpha + b * M;
        float best = -INFINITY; int bidx = 0;
        for (int m = lane; m < M; m += 64) {
            float v = row[m];
            if (v > best) { best = v; bidx = m; }
        }
        #pragma unroll
        for (int off = 1; off < 64; off <<= 1) {
            float v2 = __shfl_xor(best, off);
            int i2 = __shfl_xor(bidx, off);
            if (v2 > best || (v2 == best && i2 < bidx)) { best = v2; bidx = i2; }
        }
        float ps = 0.f;
        for (int m = lane; m < M; m += 64) ps += expf(row[m] - best);
        #pragma unroll
        for (int off = 32; off > 0; off >>= 1) ps += __shfl_xor(ps, off);
        if (lane == 0) {
            float lse = best + logf(ps);
            int tgt = span[b * 2 + phase];
            s_loss[b] = -(row[tgt] - lse);
            s_idx[b] = bidx;
        }
    }
    __syncthreads();
    if (wave == 0) {
        int b = lane;
        int active = (b < B) ? 1 : 0;
        int ni = 0, nm = 0;
        if (active) {
            int id = s_idx[b];
            if (t == 0) { nm = 1; ni = id; }
            else {
                int om = mask[b];
                ni = id * om;
                int prev = pos[b] * om;
                nm = (ni != prev) ? 1 : 0;
            }
        }
        float v = active ? s_loss[b] : 0.f;
        #pragma unroll
        for (int off = 32; off > 0; off >>= 1) v += __shfl_xor(v, off);
        float S = v * (1.0f / (float)B);
        if (active) {
            pos[b] = ni;
            mask[b] = nm;
            if (nm) { prun[b] = ni; loss_vec[b] += S; }
        }
    }
}

// ---------------- per-b: argmax + logsumexp + loss term (tier-3 path) ------------
__global__ __launch_bounds__(256) void k_softmax(
    const float* __restrict__ alpha, const int* __restrict__ span, int phase,
    float* __restrict__ loss_term, int* __restrict__ idx_out)
{
    __shared__ float sv[256];
    __shared__ int si[256];
    const int b = blockIdx.x, tid = threadIdx.x;
    const float* row = alpha + b * M;
    float best = -INFINITY; int bidx = 0;
    for (int m = tid; m < M; m += 256) {
        float v = row[m];
        if (v > best) { best = v; bidx = m; }
    }
    sv[tid] = best; si[tid] = bidx;
    __syncthreads();
    for (int s = 128; s > 0; s >>= 1) {
        if (tid < s) {
            float v2 = sv[tid + s]; int i2 = si[tid + s];
            if (v2 > sv[tid] || (v2 == sv[tid] && i2 < si[tid])) { sv[tid] = v2; si[tid] = i2; }
        }
        __syncthreads();
    }
    float bmax = sv[0]; int amax = si[0];
    __syncthreads();
    float ps = 0.f;
    for (int m = tid; m < M; m += 256) ps += expf(row[m] - bmax);
    sv[tid] = ps;
    __syncthreads();
    for (int s = 128; s > 0; s >>= 1) {
        if (tid < s) sv[tid] += sv[tid + s];
        __syncthreads();
    }
    if (tid == 0) {
        float lse = bmax + logf(sv[0]);
        int tgt = span[b * 2 + phase];
        loss_term[b] = -(row[tgt] - lse);
        idx_out[b] = amax;
    }
}

// ---------------- sticky-mask pointer update + loss (tier-3 path) ----------------
__global__ void k_update(const int* __restrict__ idx_in, const float* __restrict__ loss_term,
                         int* __restrict__ pos, int* __restrict__ mask,
                         int* __restrict__ prun, float* __restrict__ loss_vec, int t)
{
    int b = threadIdx.x;
    int active = (b < B) ? 1 : 0;
    int ni = 0, nm = 0;
    if (active) {
        int id = idx_in[b];
        if (t == 0) { nm = 1; ni = id; }
        else {
            int om = mask[b];
            ni = id * om;
            int prev = pos[b] * om;
            nm = (ni != prev) ? 1 : 0;
        }
    }
    float v = active ? loss_term[b] : 0.f;
    #pragma unroll
    for (int off = 32; off > 0; off >>= 1) v += __shfl_xor(v, off);
    float S = v * (1.0f / (float)B);
    if (active) {
        pos[b] = ni;
        mask[b] = nm;
        if (nm) { prun[b] = ni; loss_vec[b] += S; }
    }
}

// ---------------- finalize ----------------
__global__ void k_finalize(const float* __restrict__ loss_vec, const int* __restrict__ p1r,
                           const int* __restrict__ p2r, float* __restrict__ out)
{
    int b = threadIdx.x;
    float v = (b < B) ? loss_vec[b] : 0.f;
    #pragma unroll
    for (int off = 32; off > 0; off >>= 1) v += __shfl_xor(v, off);
    if (b == 0) out[0] = v / (float)(B * TSTEPS);
    if (b < B) {
        out[1 + b] = (float)p1r[b];
        out[1 + B + b] = (float)p2r[b];
    }
}

}  // namespace

extern "C" void kernel_launch(void* const* d_in, const int* in_sizes, int n_in,
                              void* d_out, int out_size, void* d_ws, size_t ws_size,
                              hipStream_t stream)
{
    const float* U      = (const float*)d_in[0];
    const int*   d_mask = (const int*)d_in[1];
    const int*   span   = (const int*)d_in[2];
    const float* W_ih   = (const float*)d_in[3];
    const float* W_hh   = (const float*)d_in[4];
    const float* b_ih   = (const float*)d_in[5];
    const float* b_hh   = (const float*)d_in[6];
    const float* Ws_lin = (const float*)d_in[7];
    const float* Ws_m1  = (const float*)d_in[8];
    const float* bs_m1  = (const float*)d_in[9];
    const float* Ws_m2  = (const float*)d_in[10];
    const float* bs_m2  = (const float*)d_in[11];
    const float* Ws_m12 = (const float*)d_in[12];
    const float* bs_m12 = (const float*)d_in[13];
    const float* We_lin = (const float*)d_in[14];
    const float* We_m1  = (const float*)d_in[15];
    const float* be_m1  = (const float*)d_in[16];
    const float* We_m2  = (const float*)d_in[17];
    const float* be_m2  = (const float*)d_in[18];
    const float* We_m12 = (const float*)d_in[19];
    const float* be_m12 = (const float*)d_in[20];

    // ---- workspace layout ----
    float* ws = (float*)d_ws;
    size_t o = 0;
    float* m2b   = ws + o; o += (size_t)BM * H;
    float* alphab= ws + o; o += BM;
    float* u_cat = ws + o; o += B * FOURH;
    float* gbuf  = ws + o; o += B * FOURH;
    float* hbuf  = ws + o; o += B * H;
    float* cbuf  = ws + o; o += B * H;
    float* rbuf  = ws + o; o += B * H;
    float* rWb   = ws + o; o += B * HP;
    float* loss_term = ws + o; o += B;
    float* loss_vec  = ws + o; o += B;
    int* ib = (int*)(ws + o); o += 8 * B + 160;   // int block + 150 tile flags
    int* idxb   = ib + 0 * B;
    int* s_i    = ib + 1 * B;
    int* e_i    = ib + 2 * B;
    int* mask_s = ib + 3 * B;
    int* mask_e = ib + 4 * B;
    int* p1r    = ib + 5 * B;
    int* p2r    = ib + 6 * B;
    int* flags  = ib + 8 * B;
    size_t o_common = (o + 3) & ~(size_t)3;

    // tier 3 (fp32 fallback): m1b fp32 (aliases the fp16 region; paths exclusive)
    float* m1b = ws + o_common;

    // tiers 15/16/2: fp16 region
    _Float16* hs = (_Float16*)(ws + o_common);
    size_t q = 0;
    _Float16* Uh    = hs + q; q += (size_t)BM * TWOH;
    _Float16* W1s   = hs + q; q += (size_t)HP * TWOH;
    _Float16* W1e   = hs + q; q += (size_t)HP * TWOH;
    _Float16* W2s   = hs + q; q += (size_t)HP * H;
    _Float16* W2e   = hs + q; q += (size_t)HP * H;
    _Float16* m1b16 = hs + q; q += (size_t)BM * H;
    _Float16* Wth_s = hs + q; q += (size_t)H * HP;   // fp16 transposed rW weights
    _Float16* Wth_e = hs + q; q += (size_t)H * HP;
    _Float16* W12sh = hs + q; q += 16 * 512;
    _Float16* W12eh = hs + q; q += 16 * 512;
    q = (q + 7) & ~(size_t)7;
    const size_t need2 = o_common * sizeof(float) + q * sizeof(_Float16);
    _Float16* A_s16 = hs + q;                    // s-side iteration-invariant A (157 MB)
    _Float16* A_e16 = A_s16 + (size_t)BM * HP;   // e-side iteration-invariant A (157 MB)
    const size_t need15s = need2 + (size_t)BM * HP * sizeof(_Float16);
    const size_t need16  = need15s + (size_t)BM * HP * sizeof(_Float16);

    // m2 in fp16 for tiers != 3 (aliases the m2b region)
    _Float16* m2h = (_Float16*)m2b;

    const int tier = (ws_size >= need16) ? 16
                   : (ws_size >= need15s) ? 15
                   : (ws_size >= need2) ? 2 : 3;

    k_init<<<1, 256, 0, stream>>>(d_mask, hbuf, cbuf, loss_vec, s_i, e_i, p1r, p2r);

    if (tier != 3) {
        // rebuild every call (ws re-poisoned by harness)
        k_flags<<<NTILES, 128, 0, stream>>>(d_mask, flags);
        k_cvtH<<<BM * TWOH / 4 / 256, 256, 0, stream>>>(U, TWOH, TWOH, Uh);
        k_cvtH<<<HP * TWOH / 4 / 256, 256, 0, stream>>>(Ws_m1, THREEH, TWOH, W1s);
        k_cvtH<<<HP * TWOH / 4 / 256, 256, 0, stream>>>(We_m1, THREEH, TWOH, W1e);
        k_cvtH<<<HP * H / 4 / 256, 256, 0, stream>>>(Ws_m2, H, H, W2s);
        k_cvtH<<<HP * H / 4 / 256, 256, 0, stream>>>(We_m2, H, H, W2e);
        k_cvtH<<<16 * 512 / 4 / 256, 256, 0, stream>>>(Ws_m12, 512, 512, W12sh);
        k_cvtH<<<16 * 512 / 4 / 256, 256, 0, stream>>>(We_m12, 512, 512, W12eh);
        k_transp2<<<1024, 256, 0, stream>>>(Ws_m1, Wth_s);
        k_transp2<<<1024, 256, 0, stream>>>(We_m1, Wth_e);

        dim3 gJ(HP / 128, NTILES);  // (32, 150)
        if (tier >= 15) {
            // iteration-invariant A_s = U @ Ws_m1[:, :512].T, fp16 (157 MB).
            gemmJ<4><<<gJ, 256, 0, stream>>>(Uh, W1s, TWOH, nullptr, flags, nullptr, A_s16);
        }
        if (tier == 16) {
            gemmJ<4><<<gJ, 256, 0, stream>>>(Uh, W1e, TWOH, nullptr, flags, nullptr, A_e16);
        }

        for (int t = 0; t < TSTEPS; ++t) {
            k_lstm_gemm2<<<128, 256, 0, stream>>>(U, s_i, e_i, hbuf, W_ih, W_hh, b_ih, b_hh, gbuf);
            k_lstm_gates<<<32, 256, 0, stream>>>(gbuf, hbuf, cbuf);

            // ---- start pointer ----
            k_r2<<<128, 256, 0, stream>>>(hbuf, U, s_i, e_i, Ws_lin, rbuf);
            k_rW2h<<<dim3(HP / 512, B), 256, 0, stream>>>(rbuf, Wth_s, bs_m1, rWb);
            if (tier >= 15)
                k_m1A16<<<BM * H / 256, 256, 0, stream>>>(A_s16, rWb, m1b16);
            else
                gemmJ<3><<<gJ, 256, 0, stream>>>(Uh, W1s, TWOH, rWb, flags, nullptr, m1b16);
            gemmJ<1><<<gJ, 256, 0, stream>>>(m1b16, W2s, H, bs_m2, flags, nullptr, m2h);
            k_alphaM<<<BM / 64, 256, 0, stream>>>(m1b16, m2h, W12sh, bs_m12, d_mask, alphab);
            k_smu<<<1, 1024, 0, stream>>>(alphab, span, 0, s_i, mask_s, p1r, loss_vec, t);

            // ---- end pointer (s_i now updated; direct U reads pick it up) ----
            k_r2<<<128, 256, 0, stream>>>(hbuf, U, s_i, e_i, We_lin, rbuf);
            k_rW2h<<<dim3(HP / 512, B), 256, 0, stream>>>(rbuf, Wth_e, be_m1, rWb);
            if (tier == 16)
                k_m1A16<<<BM * H / 256, 256, 0, stream>>>(A_e16, rWb, m1b16);
            else
                gemmJ<3><<<gJ, 256, 0, stream>>>(Uh, W1e, TWOH, rWb, flags, nullptr, m1b16);
            gemmJ<1><<<gJ, 256, 0, stream>>>(m1b16, W2e, H, be_m2, flags, nullptr, m2h);
            k_alphaM<<<BM / 64, 256, 0, stream>>>(m1b16, m2h, W12eh, be_m12, d_mask, alphab);
            k_smu<<<1, 1024, 0, stream>>>(alphab, span, 1, e_i, mask_e, p2r, loss_vec, t);
        }
    } else {
        // ---- tier 3: round-2 fp32 path (known-pass) ----
        dim3 gemm_grid(HP / 64, BM / 64);
        for (int t = 0; t < TSTEPS; ++t) {
            k_gather<<<64, 256, 0, stream>>>(U, s_i, e_i, u_cat);
            k_lstm_gemm<<<128, 256, 0, stream>>>(u_cat, hbuf, W_ih, W_hh, b_ih, b_hh, gbuf);
            k_lstm_gates<<<32, 256, 0, stream>>>(gbuf, hbuf, cbuf);

            k_r<<<32, 256, 0, stream>>>(hbuf, u_cat, Ws_lin, rbuf);
            k_rW<<<512, 256, 0, stream>>>(rbuf, Ws_m1, bs_m1, rWb);
            gemm64<2><<<gemm_grid, 256, 0, stream>>>(U, TWOH, Ws_m1, THREEH, rWb, m1b, TWOH, H);
            gemm64<1><<<gemm_grid, 256, 0, stream>>>(m1b, H, Ws_m2, H, bs_m2, m2b, H, H);
            k_alpha<<<BM / 4, 256, 0, stream>>>(m1b, m2b, Ws_m12, bs_m12, d_mask, alphab);
            k_softmax<<<B, 256, 0, stream>>>(alphab, span, 0, loss_term, idxb);
            k_update<<<1, 64, 0, stream>>>(idxb, loss_term, s_i, mask_s, p1r, loss_vec, t);

            k_gather<<<64, 256, 0, stream>>>(U, s_i, e_i, u_cat);

            k_r<<<32, 256, 0, stream>>>(hbuf, u_cat, We_lin, rbuf);
            k_rW<<<512, 256, 0, stream>>>(rbuf, We_m1, be_m1, rWb);
            gemm64<2><<<gemm_grid, 256, 0, stream>>>(U, TWOH, We_m1, THREEH, rWb, m1b, TWOH, H);
            gemm64<1><<<gemm_grid, 256, 0, stream>>>(m1b, H, We_m2, H, be_m2, m2b, H, H);
            k_alpha<<<BM / 4, 256, 0, stream>>>(m1b, m2b, We_m12, be_m12, d_mask, alphab);
            k_softmax<<<B, 256, 0, stream>>>(alphab, span, 1, loss_term, idxb);
            k_update<<<1, 64, 0, stream>>>(idxb, loss_term, e_i, mask_e, p2r, loss_vec, t);
        }
    }

    k_finalize<<<1, 64, 0, stream>>>(loss_vec, p1r, p2r, (float*)d_out);
}